// Round 9
// baseline (1927.281 us; speedup 1.0000x reference)
//
#include <hip/hip_runtime.h>
#include <math.h>

// Problem constants (reference: B,T,V,E,H = 32,512,32000,300,256)
#define BB 32
#define TT_LEN 512
#define EE 300
#define KPAD 320         // EE padded to multiple of 32 for MFMA K
#define HH 256
#define G4 1024          // 4*H
#define CMAX 155         // int(round(0.3*512))+1
#define TRANS_T 10.0f    // TRANSITION/TEMP
#define NEGF -1.0e9f
#define INV_TEMP 100.0f  // 1/TEMP
#define AST_STRIDE 160   // slot-2 accesses predicated l<27

// lstm weight split: LDS part = 8 uint4-chunks (k<64, 128 KB), register part
// = 24 uint4-chunks (k=64..255). Each uint4 = 8 f16 k-values per gate column.
#define NCH_L2 8
#define NREG 24

typedef _Float16 half2v __attribute__((ext_vector_type(2)));
typedef _Float16 half8 __attribute__((ext_vector_type(8)));
typedef float f32x4 __attribute__((ext_vector_type(4)));

__device__ __forceinline__ float la(float x, float y) {
  float m = fmaxf(x, y);
  float d = fminf(x, y) - m;
  return m + __logf(1.0f + __expf(d));
}

__device__ __forceinline__ float sigm(float x) {
  return 1.0f / (1.0f + __expf(-x));
}

__device__ __forceinline__ float dot2acc(unsigned int wd, unsigned int hd, float acc) {
#if __has_builtin(__builtin_amdgcn_fdot2)
  return __builtin_amdgcn_fdot2(__builtin_bit_cast(half2v, wd),
                                __builtin_bit_cast(half2v, hd), acc, false);
#else
  half2v a = __builtin_bit_cast(half2v, wd);
  half2v b = __builtin_bit_cast(half2v, hd);
  return acc + (float)a.x * (float)b.x + (float)a.y * (float)b.y;
#endif
}

__device__ __forceinline__ unsigned int packh(float a, float b) {
  half2v hp;
  hp.x = (_Float16)a;
  hp.y = (_Float16)b;
  return __builtin_bit_cast(unsigned int, hp);
}

// lane-broadcast of one h dword via readlane (VALU->SGPR; constant lane idx
// under full unroll; v_dot2 takes the SGPR operand directly)
__device__ __forceinline__ unsigned int rl(unsigned int v, int l) {
  return (unsigned int)__builtin_amdgcn_readlane((int)v, l);
}

// ---------------- K0: weight prep ------------------------------------------
// wi_t: f16 [dir][j'][k], j' = u*4+g, k padded to KPAD (zeros k>=300).
// wh packed f16 dwords (dword = k-pair (2k,2k+1) of gate column j):
//   LDS part  wlds_h: idx ((dir*NCH_L2 + c)*1024 + j)*4 + d, k0 = 8c+2d
//   reg part  wstr_h: idx ((dir*NREG + g)*1024 + j)*4 + d, k0 = 64+8g+2d
__global__ void prep_weights(const float* wi_f, const float* wi_b,
                             const float* wh_f, const float* wh_b,
                             const float* b_f, const float* b_b,
                             _Float16* wi_t, float* b_p,
                             unsigned int* wlds_h, unsigned int* wstr_h) {
  int idx = blockIdx.x * blockDim.x + threadIdx.x;
  int stride = gridDim.x * blockDim.x;
  // wi transpose: 2 * 1024 * KPAD f16
  for (int i = idx; i < 2 * G4 * KPAD; i += stride) {
    int dir = i / (G4 * KPAD);
    int r = i % (G4 * KPAD);
    int j = r / KPAD;
    int k = r % KPAD;
    int g = j & 3, u = j >> 2;
    const float* src = dir ? wi_b : wi_f;
    wi_t[i] = (k < EE) ? (_Float16)src[(size_t)k * G4 + g * HH + u] : (_Float16)0.0f;
  }
  // LDS-part dwords: 2 * NCH_L2 * 1024 * 4
  for (int i = idx; i < 2 * NCH_L2 * 4096; i += stride) {
    int dir = i / (NCH_L2 * 4096);
    int r = i % (NCH_L2 * 4096);
    int c = r / 4096;
    int r2 = r % 4096;
    int j = r2 >> 2, d = r2 & 3;
    int g = j & 3, u = j >> 2;
    int k0 = 8 * c + 2 * d;
    const float* src = dir ? wh_b : wh_f;
    wlds_h[i] = packh(src[k0 * G4 + g * HH + u], src[(k0 + 1) * G4 + g * HH + u]);
  }
  // register-part dwords: 2 * NREG * 1024 * 4
  for (int i = idx; i < 2 * NREG * 4096; i += stride) {
    int dir = i / (NREG * 4096);
    int r = i % (NREG * 4096);
    int gch = r / 4096;
    int r2 = r % 4096;
    int j = r2 >> 2, d = r2 & 3;
    int g = j & 3, u = j >> 2;
    int k0 = 64 + 8 * gch + 2 * d;
    const float* src = dir ? wh_b : wh_f;
    wstr_h[i] = packh(src[k0 * G4 + g * HH + u], src[(k0 + 1) * G4 + g * HH + u]);
  }
  for (int i = idx; i < 2 * G4; i += stride) {
    int dir = i / G4;
    int j = i % G4;
    int g = j & 3, u = j >> 2;
    const float* src = dir ? b_b : b_f;
    b_p[i] = src[g * HH + u];
  }
}

// ---------------- K_emb: gather embedding rows -> f16 dense (B*T, KPAD) ----
__global__ void gather_emb(const int* x, const float* embed, _Float16* emb_h) {
  int row = blockIdx.x;
  int v = x[row];
  const float* src = embed + (size_t)v * EE;
  _Float16* dst = emb_h + (size_t)row * KPAD;
  for (int k = threadIdx.x; k < KPAD; k += blockDim.x)
    dst[k] = (k < EE) ? (_Float16)src[k] : (_Float16)0.0f;
}

// ---------------- K1: xg = emb_h @ wi_t^T + b_p  (f16 MFMA) ----------------
__global__ __launch_bounds__(256) void xg_mfma(
    const _Float16* __restrict__ emb_h, const _Float16* __restrict__ wi_t,
    const float* __restrict__ b_p, float* __restrict__ xg) {
  int dir = blockIdx.z;
  int n0 = blockIdx.x * 64;
  int m0 = blockIdx.y * 64;
  int wave = threadIdx.x >> 6;
  int lane = threadIdx.x & 63;
  int l15 = lane & 15, quad = lane >> 4;

  const _Float16* arow = emb_h + (size_t)(m0 + wave * 16 + l15) * KPAD + quad * 8;
  const _Float16* bbase =
      wi_t + ((size_t)dir * G4 + n0 + l15) * KPAD + quad * 8;

  f32x4 acc[4];
#pragma unroll
  for (int nt = 0; nt < 4; ++nt) acc[nt] = (f32x4){0.f, 0.f, 0.f, 0.f};

#pragma unroll
  for (int kk = 0; kk < KPAD / 32; ++kk) {
    half8 a = *(const half8*)(arow + kk * 32);
#pragma unroll
    for (int nt = 0; nt < 4; ++nt) {
      half8 b = *(const half8*)(bbase + (size_t)nt * 16 * KPAD + kk * 32);
      acc[nt] = __builtin_amdgcn_mfma_f32_16x16x32_f16(a, b, acc[nt], 0, 0, 0);
    }
  }
#pragma unroll
  for (int nt = 0; nt < 4; ++nt) {
    int n = n0 + nt * 16 + l15;
    float bias = b_p[dir * G4 + n];
#pragma unroll
    for (int r = 0; r < 4; ++r) {
      int m = m0 + wave * 16 + quad * 4 + r;
      xg[((size_t)dir * (BB * TT_LEN) + m) * G4 + n] = acc[nt][r] + bias;
    }
  }
}

// ---------------- K2: LSTM recurrence, readlane h-broadcast ----------------
// 64 blocks (dir,b), 512 threads (8 waves, pinned 2/SIMD). Thread t owns gate
// columns t and t+512. Weights: k<64 in LDS (128 KB); k=64..255 in regs/AGPR.
// h distribution: 2 ds_read_b32/thread (hpk[lane], hpk[64+lane]) then
// readlane broadcasts -> LDS instr/step drops 384 -> 144 (the round-8
// bottleneck was 256 h-broadcast ds_read_b128 ~= 4600 cy/step).
__global__ __attribute__((amdgpu_flat_work_group_size(512, 512),
                          amdgpu_waves_per_eu(2, 2))) void lstm_v3(
    const float* __restrict__ xg, const unsigned int* __restrict__ wlds_h,
    const uint4* __restrict__ wstr, const float* __restrict__ w_out,
    float* __restrict__ scores_part) {
  int bid = blockIdx.x;            // 64 blocks: dir*32 + b
  int dir = bid >> 5, b = bid & 31;
  int t = threadIdx.x;             // 0..511
  int lane = t & 63, wid = t >> 6;

  __shared__ uint4 wlds[NCH_L2 * 1024];  // 128 KB
  __shared__ unsigned int hpk[128];      // 256 h as packed-f16 dwords
  __shared__ float gates[1024];
  __shared__ float wpart[2][4];

  // stage LDS weight part (contiguous 128 KB per dir)
  const uint4* wsrcl = (const uint4*)wlds_h + (size_t)dir * (NCH_L2 * 1024);
  for (int i = t; i < NCH_L2 * 1024; i += 512) wlds[i] = wsrcl[i];
  // load register weight part (coalesced per wave)
  const uint4* wsb = wstr + (size_t)dir * (NREG * 1024);
  uint4 wr0[NREG], wr1[NREG];
#pragma unroll
  for (int g = 0; g < NREG; ++g) {
    wr0[g] = wsb[g * 1024 + t];
    wr1[g] = wsb[g * 1024 + t + 512];
  }
  if (t < 128) hpk[t] = 0;
  __syncthreads();

  const float* xgbase =
      xg + (size_t)(dir * (BB * TT_LEN) + b * TT_LEN) * G4 + t;
  float wo = (t < HH) ? w_out[dir * HH + t] : 0.0f;
  float cstate = 0.0f;

  int t0 = dir ? (TT_LEN - 1) : 0;
  float xgn0 = xgbase[(size_t)t0 * G4];
  float xgn1 = xgbase[(size_t)t0 * G4 + 512];

#pragma unroll 1
  for (int s = 0; s < TT_LEN; ++s) {
    int tt = dir ? (TT_LEN - 1 - s) : s;
    // whole h vector into this wave's lanes: 2 LDS dword reads
    unsigned int vh0 = hpk[lane];
    unsigned int vh1 = hpk[64 + lane];
    float acc0a = xgn0, acc1a = xgn1;
    float acc0b = 0.0f, acc1b = 0.0f;
    if (s + 1 < TT_LEN) {
      int t2 = dir ? (TT_LEN - 2 - s) : (s + 1);
      xgn0 = xgbase[(size_t)t2 * G4];
      xgn1 = xgbase[(size_t)t2 * G4 + 512];
    }
    // LDS-resident weights: chunks 0..7 (h dwords 0..31 -> vh0)
#pragma unroll
    for (int c = 0; c < NCH_L2; ++c) {
      uint4 w0 = wlds[c * 1024 + t];
      uint4 w1 = wlds[c * 1024 + 512 + t];
      unsigned int h0 = rl(vh0, 4 * c + 0);
      unsigned int h1 = rl(vh0, 4 * c + 1);
      unsigned int h2 = rl(vh0, 4 * c + 2);
      unsigned int h3 = rl(vh0, 4 * c + 3);
      acc0a = dot2acc(w0.x, h0, acc0a);
      acc0a = dot2acc(w0.y, h1, acc0a);
      acc0a = dot2acc(w0.z, h2, acc0a);
      acc0a = dot2acc(w0.w, h3, acc0a);
      acc1a = dot2acc(w1.x, h0, acc1a);
      acc1a = dot2acc(w1.y, h1, acc1a);
      acc1a = dot2acc(w1.z, h2, acc1a);
      acc1a = dot2acc(w1.w, h3, acc1a);
    }
    // register weights: chunks 8..31 (h dwords 32..127)
#pragma unroll
    for (int g = 0; g < NREG; ++g) {
      int d0 = 32 + 4 * g;
      unsigned int h0 = (d0 + 0 < 64) ? rl(vh0, d0 + 0) : rl(vh1, d0 - 64);
      unsigned int h1 = (d0 + 1 < 64) ? rl(vh0, d0 + 1) : rl(vh1, d0 - 63);
      unsigned int h2 = (d0 + 2 < 64) ? rl(vh0, d0 + 2) : rl(vh1, d0 - 62);
      unsigned int h3 = (d0 + 3 < 64) ? rl(vh0, d0 + 3) : rl(vh1, d0 - 61);
      if (g < 8) {
        acc0a = dot2acc(wr0[g].x, h0, acc0a);
        acc0a = dot2acc(wr0[g].y, h1, acc0a);
        acc0a = dot2acc(wr0[g].z, h2, acc0a);
        acc0a = dot2acc(wr0[g].w, h3, acc0a);
        acc1a = dot2acc(wr1[g].x, h0, acc1a);
        acc1a = dot2acc(wr1[g].y, h1, acc1a);
        acc1a = dot2acc(wr1[g].z, h2, acc1a);
        acc1a = dot2acc(wr1[g].w, h3, acc1a);
      } else {
        acc0b = dot2acc(wr0[g].x, h0, acc0b);
        acc0b = dot2acc(wr0[g].y, h1, acc0b);
        acc0b = dot2acc(wr0[g].z, h2, acc0b);
        acc0b = dot2acc(wr0[g].w, h3, acc0b);
        acc1b = dot2acc(wr1[g].x, h0, acc1b);
        acc1b = dot2acc(wr1[g].y, h1, acc1b);
        acc1b = dot2acc(wr1[g].z, h2, acc1b);
        acc1b = dot2acc(wr1[g].w, h3, acc1b);
      }
    }
    gates[t] = acc0a + acc0b;
    gates[512 + t] = acc1a + acc1b;
    __syncthreads();

    if (t < HH) {
      float4 g4 = ((const float4*)gates)[t];
      float ig = sigm(g4.x);
      float fg = sigm(g4.y);
      float gg = tanhf(g4.z);
      float og = sigm(g4.w);
      cstate = fg * cstate + ig * gg;
      float h = og * tanhf(cstate);
      float prod = h * wo;
#pragma unroll
      for (int off = 32; off > 0; off >>= 1) prod += __shfl_down(prod, off, 64);
      if (lane == 0) wpart[s & 1][wid] = prod;
      float hn = __shfl_down(h, 1, 64);
      if (!(t & 1)) hpk[t >> 1] = packh(h, hn);
    }
    __syncthreads();
    if (t == 0) {
      scores_part[(size_t)(dir * BB + b) * TT_LEN + tt] =
          wpart[s & 1][0] + wpart[s & 1][1] + wpart[s & 1][2] + wpart[s & 1][3];
    }
  }
}

// ---------------- K4: CRF forward-backward, single wave per batch ----------
__global__ __launch_bounds__(64) void dp2(const float* __restrict__ scores_part,
                                          const float* __restrict__ b_out,
                                          float* __restrict__ ast_g,
                                          float* __restrict__ out) {
  int b = blockIdx.x;
  int l = threadIdx.x;  // 0..63
  const float* spf = scores_part + (size_t)b * TT_LEN;
  const float* spb = scores_part + (size_t)(BB + b) * TT_LEN;
  float bo = b_out[0];
  float* ast = ast_g + (size_t)b * TT_LEN * AST_STRIDE;

  float ur[8];
#pragma unroll
  for (int i = 0; i < 8; ++i)
    ur[i] = (spf[i * 64 + l] + spb[i * 64 + l] + bo) * INV_TEMP;

  int lm1 = (l + 63) & 63;
  int lp1 = (l + 1) & 63;

  float a0[3], a1[3];
  float u00 = __shfl(ur[0], 0, 64);
  a0[0] = (l == 1) ? (u00 + TRANS_T) : NEGF;
  a0[1] = NEGF;
  a0[2] = NEGF;
  a1[0] = (l == 0) ? 0.0f : NEGF;
  a1[1] = NEGF;
  a1[2] = NEGF;
  ast[l] = a0[0];
  ast[64 + l] = a0[1];
  if (l < 27) ast[128 + l] = a0[2];

  // ---- forward t = 1..511 ----
#pragma unroll
  for (int ch = 0; ch < 8; ++ch) {
    float uc = ur[ch];
#pragma unroll 1
    for (int tt = (ch == 0 ? 1 : 0); tt < 64; ++tt) {
      int t = ch * 64 + tt;
      float u0t = __shfl(uc, tt, 64);
      float w0a = __shfl(a0[0], lm1, 64);
      float w1a = __shfl(a0[1], lm1, 64);
      float w2a = __shfl(a0[2], lm1, 64);
      float w0b = __shfl(a1[0], lm1, 64);
      float w1b = __shfl(a1[1], lm1, 64);
      float w2b = __shfl(a1[2], lm1, 64);
      float p0a = (l == 0) ? NEGF : w0a;
      float p1a = (l == 0) ? w0a : w1a;
      float p2a = (l == 0) ? w1a : w2a;
      float p0b = (l == 0) ? NEGF : w0b;
      float p1b = (l == 0) ? w0b : w1b;
      float p2b = (l == 0) ? w1b : w2b;
      float n00 = u0t + la(p0a + TRANS_T, p0b);
      float n01 = u0t + la(p1a + TRANS_T, p1b);
      float n02 = u0t + la(p2a + TRANS_T, p2b);
      float n10 = la(a0[0], a1[0]);
      float n11 = la(a0[1], a1[1]);
      float n12 = la(a0[2], a1[2]);
      a0[0] = n00;
      a0[1] = n01;
      a0[2] = (l < 27) ? n02 : NEGF;
      a1[0] = n10;
      a1[1] = n11;
      a1[2] = (l < 27) ? n12 : NEGF;
      float* astr = ast + (size_t)t * AST_STRIDE;
      astr[l] = a0[0];
      astr[64 + l] = a0[1];
      if (l < 27) astr[128 + l] = a0[2];
    }
  }

  // ---- logZ ----
  float f00 = a0[0] + TRANS_T, f01 = a0[1] + TRANS_T, f02 = a0[2] + TRANS_T;
  float m = fmaxf(fmaxf(fmaxf(f00, f01), fmaxf(f02, a1[0])), fmaxf(a1[1], a1[2]));
#pragma unroll
  for (int off = 32; off > 0; off >>= 1) m = fmaxf(m, __shfl_xor(m, off, 64));
  float es = __expf(f00 - m) + __expf(f01 - m) + __expf(f02 - m) +
             __expf(a1[0] - m) + __expf(a1[1] - m) + __expf(a1[2] - m);
#pragma unroll
  for (int off = 32; off > 0; off >>= 1) es += __shfl_xor(es, off, 64);
  float lz = m + __logf(es);

  // ---- backward init (t = 511) ----
  float b0[3], b1[3];
  b0[0] = TRANS_T;
  b0[1] = TRANS_T;
  b0[2] = (l < 27) ? TRANS_T : NEGF;
  b1[0] = 0.0f;
  b1[1] = 0.0f;
  b1[2] = (l < 27) ? 0.0f : NEGF;
  {
    float ts = __expf(a0[0] + TRANS_T - lz) + __expf(a0[1] + TRANS_T - lz) +
               ((l < 27) ? __expf(a0[2] + TRANS_T - lz) : 0.0f);
#pragma unroll
    for (int off = 32; off > 0; off >>= 1) ts += __shfl_xor(ts, off, 64);
    if (l == 0) out[b * TT_LEN + (TT_LEN - 1)] = ts;
  }

  float nr0 = ast[(size_t)510 * AST_STRIDE + l];
  float nr1 = ast[(size_t)510 * AST_STRIDE + 64 + l];
  float nr2 = (l < 27) ? ast[(size_t)510 * AST_STRIDE + 128 + l] : NEGF;

  // ---- backward t = 511..1 ----
#pragma unroll
  for (int ch = 7; ch >= 0; --ch) {
    float uc = ur[ch];
#pragma unroll 1
    for (int tt = 63; tt >= (ch == 0 ? 1 : 0); --tt) {
      int t = ch * 64 + tt;
      float u0t = __shfl(uc, tt, 64);
      float c0 = nr0, c1 = nr1, c2 = nr2;
      if (t >= 2) {
        const float* astr = ast + (size_t)(t - 2) * AST_STRIDE;
        nr0 = astr[l];
        nr1 = astr[64 + l];
        nr2 = (l < 27) ? astr[128 + l] : NEGF;
      }
      float w0 = __shfl(b0[0], lp1, 64);
      float w1 = __shfl(b0[1], lp1, 64);
      float w2 = __shfl(b0[2], lp1, 64);
      float x2 = (l == 63) ? NEGF : w2;
      float x1 = (l == 63) ? w2 : w1;
      float x0 = (l == 63) ? w1 : w0;
      float nb00 = la(u0t + TRANS_T + x0, b1[0]);
      float nb01 = la(u0t + TRANS_T + x1, b1[1]);
      float nb02 = la(u0t + TRANS_T + x2, b1[2]);
      float nb10 = la(u0t + x0, b1[0]);
      float nb11 = la(u0t + x1, b1[1]);
      float nb12 = la(u0t + x2, b1[2]);
      float tm = __expf(c0 + nb00 - lz) + __expf(c1 + nb01 - lz) +
                 ((l < 27) ? __expf(c2 + nb02 - lz) : 0.0f);
#pragma unroll
      for (int off = 32; off > 0; off >>= 1) tm += __shfl_xor(tm, off, 64);
      if (l == 0) out[b * TT_LEN + (t - 1)] = tm;
      b0[0] = nb00;
      b0[1] = nb01;
      b0[2] = (l < 27) ? nb02 : NEGF;
      b1[0] = nb10;
      b1[1] = nb11;
      b1[2] = (l < 27) ? nb12 : NEGF;
    }
  }
}

// ---------------------------------------------------------------------------
extern "C" void kernel_launch(void* const* d_in, const int* in_sizes, int n_in,
                              void* d_out, int out_size, void* d_ws, size_t ws_size,
                              hipStream_t stream) {
  const int* x = (const int*)d_in[0];
  const float* embed = (const float*)d_in[3];
  const float* wi_f = (const float*)d_in[4];
  const float* wh_f = (const float*)d_in[5];
  const float* bf = (const float*)d_in[6];
  const float* wi_b = (const float*)d_in[7];
  const float* wh_b = (const float*)d_in[8];
  const float* bbias = (const float*)d_in[9];
  const float* w_out = (const float*)d_in[10];
  const float* b_out = (const float*)d_in[11];

  float* ws = (float*)d_ws;
  float* b_p = ws;                                      // 2*1024 f32
  unsigned int* wlds_h = (unsigned int*)(b_p + 2 * G4); // 2*8*4096 dwords
  unsigned int* wstr_h = wlds_h + 2 * NCH_L2 * 4096;    // 2*24*4096 dwords
  _Float16* wi_t = (_Float16*)(wstr_h + 2 * NREG * 4096);  // 2*1024*320 f16
  _Float16* emb_h = wi_t + (size_t)2 * G4 * KPAD;       // 16384*320 f16
  float* xg = (float*)(emb_h + (size_t)BB * TT_LEN * KPAD);  // 2*16384*1024 f32
  float* scores_part = xg + (size_t)2 * BB * TT_LEN * G4;    // 2*16384
  float* u0_unused = scores_part + 2 * BB * TT_LEN;     // 16384 (layout keep)
  float* ast_g = u0_unused + BB * TT_LEN;               // 32*512*160 f32
  float* outp = (float*)d_out;

  prep_weights<<<256, 256, 0, stream>>>(wi_f, wi_b, wh_f, wh_b, bf, bbias,
                                        wi_t, b_p, wlds_h, wstr_h);
  gather_emb<<<BB * TT_LEN, 256, 0, stream>>>(x, embed, emb_h);
  dim3 g1(G4 / 64, (BB * TT_LEN) / 64, 2);
  xg_mfma<<<g1, 256, 0, stream>>>(emb_h, wi_t, b_p, xg);
  lstm_v3<<<64, 512, 0, stream>>>(xg, wlds_h, (const uint4*)wstr_h, w_out,
                                  scores_part);
  dp2<<<BB, 64, 0, stream>>>(scores_part, b_out, ast_g, outp);
}